// Round 2
// baseline (5511.126 us; speedup 1.0000x reference)
//
#include <hip/hip_runtime.h>
#include <hip/hip_bf16.h>
#include <math.h>

// Problem constants (from reference)
constexpr int NN = 100000;     // nodes
constexpr int NE = 3200000;    // edges
constexpr int HID = 256;

// bf16 <-> fp32 helpers (storage-only bf16; all math fp32)
__device__ __forceinline__ float bf2f(unsigned short u) {
    unsigned int t = ((unsigned int)u) << 16;
    float f;
    __builtin_memcpy(&f, &t, 4);
    return f;
}
__device__ __forceinline__ unsigned short f2bf(float f) {
    unsigned int t;
    __builtin_memcpy(&t, &f, 4);
    unsigned int lsb = (t >> 16) & 1u;
    t += 0x7fffu + lsb;          // round-to-nearest-even
    return (unsigned short)(t >> 16);
}

// ---------------------------------------------------------------------------
// Edge dtype detection: reference dtype is int64 but harness may deliver
// int32. If the first 64 odd 32-bit words are all zero -> int64 (high words
// of node ids < 100000). Deterministic per call.
// ---------------------------------------------------------------------------
__global__ void detect_i64(const int* __restrict__ ei, int* __restrict__ flag) {
    if (blockIdx.x == 0 && threadIdx.x == 0) {
        int z = 1;
        for (int i = 0; i < 64; ++i) {
            if (ei[2 * i + 1] != 0) { z = 0; break; }
        }
        *flag = z;
    }
}

__device__ __forceinline__ int load_edge(const int* ei, int is64, long long idx) {
    if (is64) {
        long long v = ((const long long*)ei)[idx];
        return (int)v;
    }
    return ei[idx];
}

// ---------------------------------------------------------------------------
// Setup: zero degree counters, cursors, gsum (ws is poisoned 0xAA each call)
// ---------------------------------------------------------------------------
__global__ void zero_setup(int* __restrict__ cnt, int* __restrict__ cursor,
                           float* __restrict__ gsum) {
    int i = blockIdx.x * 256 + threadIdx.x;
    if (i < NN) { cnt[i] = 0; cursor[i] = 0; }
    if (i < HID) gsum[i] = 0.0f;
}

// ---------------------------------------------------------------------------
// CSR construction
// ---------------------------------------------------------------------------
__global__ void count_deg(const int* __restrict__ ei, const int* __restrict__ flag,
                          int* __restrict__ cnt) {
    int e = blockIdx.x * 256 + threadIdx.x;
    if (e >= NE) return;
    int is64 = *flag;
    int d = load_edge(ei, is64, (long long)NE + e);
    d = min(max(d, 0), NN - 1);
    atomicAdd(&cnt[d], 1);
}

// Single-block scan over 100000 counts -> exclusive offsets (off[NN] = total)
__global__ void scan_offsets(const int* __restrict__ cnt, int* __restrict__ off) {
    __shared__ int sdata[1024];
    __shared__ int carry;
    if (threadIdx.x == 0) carry = 0;
    __syncthreads();
    for (int base = 0; base < NN; base += 1024) {
        int i = base + (int)threadIdx.x;
        int v = (i < NN) ? cnt[i] : 0;
        sdata[threadIdx.x] = v;
        __syncthreads();
        for (int ofs = 1; ofs < 1024; ofs <<= 1) {
            int t = (threadIdx.x >= (unsigned)ofs) ? sdata[threadIdx.x - ofs] : 0;
            __syncthreads();
            sdata[threadIdx.x] += t;
            __syncthreads();
        }
        if (i < NN) off[i] = carry + sdata[threadIdx.x] - v;
        int total = sdata[1023];
        __syncthreads();
        if (threadIdx.x == 0) carry += total;
        __syncthreads();
    }
    if (threadIdx.x == 0) off[NN] = carry;
}

__global__ void fill_csr(const int* __restrict__ ei, const int* __restrict__ flag,
                         const int* __restrict__ off, int* __restrict__ cursor,
                         int* __restrict__ csr) {
    int e = blockIdx.x * 256 + threadIdx.x;
    if (e >= NE) return;
    int is64 = *flag;
    int s = load_edge(ei, is64, e);
    int d = load_edge(ei, is64, (long long)NE + e);
    s = min(max(s, 0), NN - 1);
    d = min(max(d, 0), NN - 1);
    int p = atomicAdd(&cursor[d], 1);
    csr[off[d] + p] = s;
}

// ---------------------------------------------------------------------------
// Input encoding: h[:, :128] = relu(x @ W_in^T + b_in); h[:, 128:] = 0
// one block per node, 128 threads (one per output feature). h stored bf16.
// ---------------------------------------------------------------------------
__global__ __launch_bounds__(128)
void input_encode(const float* __restrict__ x, const float* __restrict__ W,
                  const float* __restrict__ b, unsigned short* __restrict__ h) {
    __shared__ float xs[128];
    int n = blockIdx.x;
    int j = threadIdx.x;
    xs[j] = x[(size_t)n * 128 + j];
    __syncthreads();
    const float4* wr = (const float4*)(W + (size_t)j * 128);
    const float4* xv = (const float4*)xs;
    float acc = 0.0f;
#pragma unroll
    for (int k = 0; k < 32; ++k) {
        float4 w4 = wr[k];
        float4 x4 = xv[k];
        acc = fmaf(w4.x, x4.x, acc);
        acc = fmaf(w4.y, x4.y, acc);
        acc = fmaf(w4.z, x4.z, acc);
        acc = fmaf(w4.w, x4.w, acc);
    }
    acc += b[j];
    h[(size_t)n * HID + j] = f2bf(fmaxf(acc, 0.0f));
    h[(size_t)n * HID + 128 + j] = 0;   // bf16 zero
}

// ---------------------------------------------------------------------------
// Aggregation: m[n] = mean over incoming edges of h[src]. One wave per node;
// each lane holds 4 consecutive bf16 features (64 lanes * 4 = 256).
// ---------------------------------------------------------------------------
__global__ __launch_bounds__(256)
void aggregate(const unsigned short* __restrict__ h, const int* __restrict__ off,
               const int* __restrict__ csr, unsigned short* __restrict__ m) {
    int w = blockIdx.x * 4 + (threadIdx.x >> 6);   // node id
    int lane = threadIdx.x & 63;
    if (w >= NN) return;
    int e0 = off[w], e1 = off[w + 1];
    float4 acc = make_float4(0.f, 0.f, 0.f, 0.f);
    for (int e = e0; e < e1; ++e) {
        int s = csr[e];
        ushort4 v = *(const ushort4*)(h + (size_t)s * HID + lane * 4);
        acc.x += bf2f(v.x); acc.y += bf2f(v.y);
        acc.z += bf2f(v.z); acc.w += bf2f(v.w);
    }
    float inv = 1.0f / (float)max(e1 - e0, 1);
    ushort4 o;
    o.x = f2bf(acc.x * inv); o.y = f2bf(acc.y * inv);
    o.z = f2bf(acc.z * inv); o.w = f2bf(acc.w * inv);
    *(ushort4*)(m + (size_t)w * HID + lane * 4) = o;
}

// ---------------------------------------------------------------------------
// MGU fused GEMM (fp32 math, bf16 storage). K=512 view:
//   PART 1: f = sigmoid([m | h] @ [W_f ; U_f]^T + b_f)
//   PART 2: h_new = (1-f)*h + f*tanh([m | f*h] @ [W_h ; U_h]^T + b_h)
// 128x128 block tile, 8x8 micro-tile, BK=32, 256 threads.
// ---------------------------------------------------------------------------
template <int PART>
__global__ __launch_bounds__(256)
void mgu_gemm(const unsigned short* __restrict__ Mm,
              const unsigned short* __restrict__ Hh,
              const unsigned short* __restrict__ Ff,
              const float* __restrict__ Wa, const float* __restrict__ Wb,
              const float* __restrict__ bias, unsigned short* __restrict__ Out) {
    __shared__ float As[32][132];   // As[k][row]
    __shared__ float Bs[32][132];   // Bs[k][col]
    const int rowBase = blockIdx.x * 128;
    const int colBase = blockIdx.y * 128;
    const int tid = threadIdx.x;
    const int tx = tid & 15;
    const int ty = tid >> 4;
    float acc[8][8];
#pragma unroll
    for (int i = 0; i < 8; ++i)
#pragma unroll
        for (int j = 0; j < 8; ++j) acc[i][j] = 0.0f;

    for (int k0 = 0; k0 < 512; k0 += 32) {
        // ---- A tile: rows rowBase..+127, k0..k0+31 (bf16 -> fp32)
        {
            const int kg = (tid & 7) * 4;
            const int r0 = tid >> 3;        // 0..31
            const bool hi = (k0 >= 256);
            const int kk = (k0 & 255) + kg;
#pragma unroll
            for (int rr = 0; rr < 4; ++rr) {
                int r = r0 + rr * 32;
                int grow = rowBase + r;
                float4 v = make_float4(0.f, 0.f, 0.f, 0.f);
                if (grow < NN) {
                    size_t base = (size_t)grow * HID + kk;
                    if (!hi) {
                        ushort4 u = *(const ushort4*)(Mm + base);
                        v = make_float4(bf2f(u.x), bf2f(u.y), bf2f(u.z), bf2f(u.w));
                    } else if (PART == 1) {
                        ushort4 u = *(const ushort4*)(Hh + base);
                        v = make_float4(bf2f(u.x), bf2f(u.y), bf2f(u.z), bf2f(u.w));
                    } else {
                        ushort4 hu = *(const ushort4*)(Hh + base);
                        ushort4 fu = *(const ushort4*)(Ff + base);
                        v = make_float4(bf2f(hu.x) * bf2f(fu.x),
                                        bf2f(hu.y) * bf2f(fu.y),
                                        bf2f(hu.z) * bf2f(fu.z),
                                        bf2f(hu.w) * bf2f(fu.w));
                    }
                }
                As[kg + 0][r] = v.x;
                As[kg + 1][r] = v.y;
                As[kg + 2][r] = v.z;
                As[kg + 3][r] = v.w;
            }
        }
        // ---- B tile (fp32 weights): Bs[kk][j] = W[colBase+j][k0+kk]
        {
            const float* W = (k0 < 256) ? Wa : Wb;
            const int j = tid >> 1;              // 0..127
            const int kofs = (tid & 1) * 16;
            const float* wr = W + (size_t)(colBase + j) * 256 + (k0 & 255) + kofs;
#pragma unroll
            for (int q = 0; q < 4; ++q) {
                float4 v = *(const float4*)(wr + q * 4);
                Bs[kofs + q * 4 + 0][j] = v.x;
                Bs[kofs + q * 4 + 1][j] = v.y;
                Bs[kofs + q * 4 + 2][j] = v.z;
                Bs[kofs + q * 4 + 3][j] = v.w;
            }
        }
        __syncthreads();
#pragma unroll
        for (int kk = 0; kk < 32; ++kk) {
            float a[8], b[8];
            *(float4*)&a[0] = *(const float4*)&As[kk][ty * 8];
            *(float4*)&a[4] = *(const float4*)&As[kk][ty * 8 + 4];
            *(float4*)&b[0] = *(const float4*)&Bs[kk][tx * 8];
            *(float4*)&b[4] = *(const float4*)&Bs[kk][tx * 8 + 4];
#pragma unroll
            for (int i = 0; i < 8; ++i)
#pragma unroll
                for (int j = 0; j < 8; ++j)
                    acc[i][j] = fmaf(a[i], b[j], acc[i][j]);
        }
        __syncthreads();
    }

    // ---- epilogue
#pragma unroll
    for (int i = 0; i < 8; ++i) {
        int grow = rowBase + ty * 8 + i;
        if (grow < NN) {
            size_t rb = (size_t)grow * HID + colBase + tx * 8;
#pragma unroll
            for (int j = 0; j < 8; ++j) {
                int gcol = colBase + tx * 8 + j;
                float v = acc[i][j] + bias[gcol];
                if (PART == 1) {
                    Out[rb + j] = f2bf(1.0f / (1.0f + __expf(-v)));
                } else {
                    float hv = bf2f(Hh[rb + j]);
                    float fv = bf2f(Ff[rb + j]);
                    float hh = tanhf(v);
                    Out[rb + j] = f2bf((1.0f - fv) * hv + fv * hh);
                }
            }
        }
    }
}

// ---------------------------------------------------------------------------
// Readout
// ---------------------------------------------------------------------------
__global__ __launch_bounds__(256)
void colmean(const unsigned short* __restrict__ h, float* __restrict__ gsum) {
    int j = threadIdx.x;                  // feature
    long long n0 = (long long)blockIdx.x * 256;
    float acc = 0.0f;
    for (int n = 0; n < 256; ++n) {
        long long node = n0 + n;
        if (node < NN) acc += bf2f(h[node * HID + j]);
    }
    atomicAdd(&gsum[j], acc);
}

__global__ __launch_bounds__(256)
void final_pred(const float* __restrict__ gsum, const float* __restrict__ Wp,
                const float* __restrict__ bp, float* __restrict__ out) {
    __shared__ float s[256];
    int j = threadIdx.x;
    s[j] = gsum[j] * (1.0f / (float)NN) * Wp[j];
    __syncthreads();
    for (int ofs = 128; ofs > 0; ofs >>= 1) {
        if (j < ofs) s[j] += s[j + ofs];
        __syncthreads();
    }
    if (j == 0) out[0] = s[0] + bp[0];
}

// ---------------------------------------------------------------------------
extern "C" void kernel_launch(void* const* d_in, const int* in_sizes, int n_in,
                              void* d_out, int out_size, void* d_ws, size_t ws_size,
                              hipStream_t stream) {
    const float* x      = (const float*)d_in[0];
    const int*   ei     = (const int*)d_in[1];
    const float* W_in   = (const float*)d_in[2];
    const float* b_in   = (const float*)d_in[3];
    const float* W_f    = (const float*)d_in[4];
    const float* U_f    = (const float*)d_in[5];
    const float* b_f    = (const float*)d_in[6];
    const float* W_h    = (const float*)d_in[7];
    const float* U_h    = (const float*)d_in[8];
    const float* b_h    = (const float*)d_in[9];
    const float* W_pred = (const float*)d_in[10];
    const float* b_pred = (const float*)d_in[11];
    float* out = (float*)d_out;

    // workspace carve-up (512B aligned); total ~219 MB
    char* p = (char*)d_ws;
    auto alloc = [&](size_t bytes) {
        char* r = p;
        p += (bytes + 511) & ~(size_t)511;
        return r;
    };
    int*            cnt    = (int*)alloc((size_t)NN * 4);
    int*            cursor = (int*)alloc((size_t)NN * 4);
    int*            off    = (int*)alloc((size_t)(NN + 1) * 4);
    int*            flag   = (int*)alloc(4);
    float*          gsum   = (float*)alloc(HID * 4);
    int*            csr    = (int*)alloc((size_t)NE * 4);
    unsigned short* h0     = (unsigned short*)alloc((size_t)NN * HID * 2);
    unsigned short* h1     = (unsigned short*)alloc((size_t)NN * HID * 2);
    unsigned short* mbuf   = (unsigned short*)alloc((size_t)NN * HID * 2);
    unsigned short* fbuf   = (unsigned short*)alloc((size_t)NN * HID * 2);

    detect_i64<<<1, 64, 0, stream>>>(ei, flag);
    zero_setup<<<(NN + 255) / 256, 256, 0, stream>>>(cnt, cursor, gsum);
    input_encode<<<NN, 128, 0, stream>>>(x, W_in, b_in, h0);
    count_deg<<<(NE + 255) / 256, 256, 0, stream>>>(ei, flag, cnt);
    scan_offsets<<<1, 1024, 0, stream>>>(cnt, off);
    fill_csr<<<(NE + 255) / 256, 256, 0, stream>>>(ei, flag, off, cursor, csr);

    dim3 ggrid((NN + 127) / 128, 2);
    unsigned short* hc = h0;
    unsigned short* hn = h1;
    for (int step = 0; step < 4; ++step) {
        aggregate<<<NN / 4, 256, 0, stream>>>(hc, off, csr, mbuf);
        mgu_gemm<1><<<ggrid, 256, 0, stream>>>(mbuf, hc, nullptr, W_f, U_f, b_f, fbuf);
        mgu_gemm<2><<<ggrid, 256, 0, stream>>>(mbuf, hc, fbuf, W_h, U_h, b_h, hn);
        unsigned short* t = hc; hc = hn; hn = t;
    }

    colmean<<<(NN + 255) / 256, 256, 0, stream>>>(hc, gsum);
    final_pred<<<1, 256, 0, stream>>>(gsum, W_pred, b_pred, out);
}

// Round 3
// 2067.030 us; speedup vs baseline: 2.6662x; 2.6662x over previous
//
#include <hip/hip_runtime.h>
#include <hip/hip_bf16.h>
#include <math.h>

constexpr int NN = 100000;     // nodes
constexpr int NE = 3200000;    // edges
constexpr int HID = 256;
constexpr int NBLK = (NN + 255) / 256;   // 391

typedef __attribute__((ext_vector_type(8))) short short8;
typedef __attribute__((ext_vector_type(4))) float floatx4;
typedef __attribute__((ext_vector_type(8))) unsigned short ushort8v;

// ---- bf16 helpers (storage bf16, math fp32) -------------------------------
__device__ __forceinline__ float bf2f(unsigned short u) {
    unsigned int t = ((unsigned int)u) << 16;
    float f; __builtin_memcpy(&f, &t, 4); return f;
}
__device__ __forceinline__ unsigned short f2bf(float f) {
    unsigned int t; __builtin_memcpy(&t, &f, 4);
    unsigned int lsb = (t >> 16) & 1u;
    t += 0x7fffu + lsb;
    return (unsigned short)(t >> 16);
}

// async global->LDS, 16B per lane; lds base must be wave-uniform
__device__ __forceinline__ void llds16(const void* g, void* l) {
    __builtin_amdgcn_global_load_lds(
        (const __attribute__((address_space(1))) unsigned int*)g,
        (__attribute__((address_space(3))) unsigned int*)l, 16, 0, 0);
}

// ---------------------------------------------------------------------------
// Edge dtype detection (int64 vs int32 delivery)
// ---------------------------------------------------------------------------
__global__ void detect_i64(const int* __restrict__ ei, int* __restrict__ flag) {
    if (blockIdx.x == 0 && threadIdx.x == 0) {
        int z = 1;
        for (int i = 0; i < 64; ++i)
            if (ei[2 * i + 1] != 0) { z = 0; break; }
        *flag = z;
    }
}
__device__ __forceinline__ int load_edge(const int* ei, int is64, long long idx) {
    if (is64) return (int)(((const long long*)ei)[idx]);
    return ei[idx];
}

__global__ void zero_setup(int* __restrict__ cnt, int* __restrict__ cursor,
                           float* __restrict__ gsum) {
    int i = blockIdx.x * 256 + threadIdx.x;
    if (i < NN) { cnt[i] = 0; cursor[i] = 0; }
    if (i < HID) gsum[i] = 0.0f;
}

// ---------------------------------------------------------------------------
// Weight / input conversion to bf16
// wcf[n][k] = {W_f[n][k] k<256 ; U_f[n][k-256]}  (row 1 KB)   same for wch
// ---------------------------------------------------------------------------
__global__ void conv_weights(const float* __restrict__ Wf, const float* __restrict__ Uf,
                             const float* __restrict__ Wh, const float* __restrict__ Uh,
                             const float* __restrict__ Win,
                             unsigned short* __restrict__ wcf,
                             unsigned short* __restrict__ wch,
                             unsigned short* __restrict__ wib) {
    int i = blockIdx.x * 256 + threadIdx.x;
    if (i < 256 * 512) {
        int n = i >> 9, k = i & 511;
        float vf = (k < 256) ? Wf[n * 256 + k] : Uf[n * 256 + k - 256];
        float vh = (k < 256) ? Wh[n * 256 + k] : Uh[n * 256 + k - 256];
        wcf[i] = f2bf(vf); wch[i] = f2bf(vh);
    }
    if (i < 128 * 128) wib[i] = f2bf(Win[i]);
}

__global__ void conv_x(const float* __restrict__ x, unsigned short* __restrict__ xb) {
    int i = blockIdx.x * 256 + threadIdx.x;   // one float4 each
    if (i < NN * 128 / 4) {
        float4 v = ((const float4*)x)[i];
        ushort4 o;
        o.x = f2bf(v.x); o.y = f2bf(v.y); o.z = f2bf(v.z); o.w = f2bf(v.w);
        ((ushort4*)xb)[i] = o;
    }
}

// ---------------------------------------------------------------------------
// CSR construction
// ---------------------------------------------------------------------------
__global__ void count_deg(const int* __restrict__ ei, const int* __restrict__ flag,
                          int* __restrict__ cnt) {
    int e = blockIdx.x * 256 + threadIdx.x;
    if (e >= NE) return;
    int is64 = *flag;
    int d = load_edge(ei, is64, (long long)NE + e);
    d = min(max(d, 0), NN - 1);
    atomicAdd(&cnt[d], 1);
}

// hierarchical scan: k1 per-block scan, k2 scan block sums, k3 combine
__global__ void scan_k1(const int* __restrict__ cnt, int* __restrict__ loc,
                        int* __restrict__ bsum) {
    __shared__ int s[256];
    int b = blockIdx.x, t = threadIdx.x;
    int i = b * 256 + t;
    int v = (i < NN) ? cnt[i] : 0;
    s[t] = v;
    __syncthreads();
    for (int ofs = 1; ofs < 256; ofs <<= 1) {
        int tv = (t >= ofs) ? s[t - ofs] : 0;
        __syncthreads();
        s[t] += tv;
        __syncthreads();
    }
    if (i < NN) loc[i] = s[t] - v;          // exclusive
    if (t == 255) bsum[b] = s[255];
}
__global__ void scan_k2(const int* __restrict__ bsum, int* __restrict__ bpre) {
    __shared__ int s[512];
    int t = threadIdx.x;
    int v = (t < NBLK) ? bsum[t] : 0;
    s[t] = v;
    __syncthreads();
    for (int ofs = 1; ofs < 512; ofs <<= 1) {
        int tv = (t >= ofs) ? s[t - ofs] : 0;
        __syncthreads();
        s[t] += tv;
        __syncthreads();
    }
    if (t < NBLK) bpre[t] = s[t] - v;       // exclusive
    if (t == NBLK - 1) bpre[NBLK] = s[t];   // total
}
__global__ void scan_k3(const int* __restrict__ loc, const int* __restrict__ bpre,
                        int* __restrict__ off) {
    int b = blockIdx.x, t = threadIdx.x;
    int i = b * 256 + t;
    if (i < NN) off[i] = loc[i] + bpre[b];
    if (b == 0 && t == 0) off[NN] = bpre[NBLK];
}

__global__ void fill_csr(const int* __restrict__ ei, const int* __restrict__ flag,
                         const int* __restrict__ off, int* __restrict__ cursor,
                         int* __restrict__ csr) {
    int e = blockIdx.x * 256 + threadIdx.x;
    if (e >= NE) return;
    int is64 = *flag;
    int s = load_edge(ei, is64, e);
    int d = load_edge(ei, is64, (long long)NE + e);
    s = min(max(s, 0), NN - 1);
    d = min(max(d, 0), NN - 1);
    int p = atomicAdd(&cursor[d], 1);
    csr[off[d] + p] = s;
}

// ---------------------------------------------------------------------------
// Aggregation: mean of h[src] rows per node. One wave per node; each wave-load
// fetches TWO rows (half-wave per edge, ushort8 = 16B per lane), 2x unrolled.
// ---------------------------------------------------------------------------
__global__ __launch_bounds__(256)
void aggregate(const unsigned short* __restrict__ h, const int* __restrict__ off,
               const int* __restrict__ csr, unsigned short* __restrict__ m) {
    int node = blockIdx.x * 4 + (threadIdx.x >> 6);
    int lane = threadIdx.x & 63;
    int half = lane >> 5;
    int fl = lane & 31;                  // feature chunk: fl*8 .. fl*8+7
    int e0 = off[node], e1 = off[node + 1];
    float a0[8], a1[8];
#pragma unroll
    for (int k = 0; k < 8; ++k) { a0[k] = 0.f; a1[k] = 0.f; }
    int e = e0;
    for (; e + 4 <= e1; e += 4) {
        int s0 = csr[e + half];
        int s1 = csr[e + 2 + half];
        ushort8v v0 = *(const ushort8v*)(h + (size_t)s0 * HID + fl * 8);
        ushort8v v1 = *(const ushort8v*)(h + (size_t)s1 * HID + fl * 8);
#pragma unroll
        for (int k = 0; k < 8; ++k) { a0[k] += bf2f(v0[k]); a1[k] += bf2f(v1[k]); }
    }
    for (; e + 2 <= e1; e += 2) {
        int s0 = csr[e + half];
        ushort8v v0 = *(const ushort8v*)(h + (size_t)s0 * HID + fl * 8);
#pragma unroll
        for (int k = 0; k < 8; ++k) a0[k] += bf2f(v0[k]);
    }
    if (e < e1 && half == 0) {
        int s0 = csr[e];
        ushort8v v0 = *(const ushort8v*)(h + (size_t)s0 * HID + fl * 8);
#pragma unroll
        for (int k = 0; k < 8; ++k) a0[k] += bf2f(v0[k]);
    }
#pragma unroll
    for (int k = 0; k < 8; ++k) a0[k] += a1[k];
#pragma unroll
    for (int k = 0; k < 8; ++k) a0[k] += __shfl(a0[k], lane ^ 32, 64);
    float inv = 1.0f / (float)max(e1 - e0, 1);
    if (half == 0) {
        ushort8v o;
#pragma unroll
        for (int k = 0; k < 8; ++k) o[k] = f2bf(a0[k] * inv);
        *(ushort8v*)(m + (size_t)node * HID + fl * 8) = o;
    }
}

// ---------------------------------------------------------------------------
// MFMA GEMM, 128x128 tile, 4 waves (2x2), each wave 4x4 of 16x16x32 bf16.
// A = [A0 | A1] along K (bf16, row stride ASTR bytes). B = bf16 [n][k] rows.
// MODE 0: encode  K=128: out = relu(v+bias) -> Out[:, :128]; Out[:,128:] = 0
// MODE 1: gate    K=512: f = sigmoid(v+bias) -> Ff;  HF = f * Hh
// MODE 2: cand    K=512: Out(=Hh) = (1-f)*h + f*tanh(v+bias)   (in place)
// ---------------------------------------------------------------------------
template <int MODE>
__global__ __launch_bounds__(256)
void gemm_mfma(const unsigned short* __restrict__ A0,
               const unsigned short* __restrict__ A1,
               const unsigned short* __restrict__ Bw,
               const float* __restrict__ bias,
               const unsigned short* Hh,     // MODE1: read h; MODE2: read h
               unsigned short* Ff,           // MODE1: write f; MODE2: read f
               unsigned short* HF,           // MODE1: write f*h
               unsigned short* Out) {        // MODE0: h; MODE2: h (in place)
    constexpr int KTOT = (MODE == 0) ? 128 : 512;
    constexpr int ASTR = (MODE == 0) ? 256 : 512;    // bytes per A row
    constexpr int BSTR = (MODE == 0) ? 256 : 1024;   // bytes per B row

    __shared__ unsigned short As[128 * 32];
    __shared__ unsigned short Bs[128 * 32];

    const int tid = threadIdx.x;
    const int wave = tid >> 6, lane = tid & 63;
    const int wr = (wave >> 1) * 64, wc = (wave & 1) * 64;
    const int lq = lane >> 4, lm = lane & 15;
    const int rowBase = blockIdx.x * 128;
    const int colBase = blockIdx.y * 128;

    floatx4 acc[4][4];
#pragma unroll
    for (int i = 0; i < 4; ++i)
#pragma unroll
        for (int j = 0; j < 4; ++j) {
            acc[i][j][0] = 0.f; acc[i][j][1] = 0.f;
            acc[i][j][2] = 0.f; acc[i][j][3] = 0.f;
        }

    for (int k0 = 0; k0 < KTOT; k0 += 32) {
        const unsigned short* Ak;
        int kc;
        if (MODE != 0 && k0 >= 256) { Ak = A1; kc = k0 - 256; }
        else                         { Ak = A0; kc = k0; }
#pragma unroll
        for (int q = 0; q < 2; ++q) {
            int id = wave * 128 + q * 64 + lane;
            int r = id >> 2, c = id & 3;
            int grow = rowBase + r;
            if (grow > NN - 1) grow = NN - 1;
            const char* ga = (const char*)Ak + (size_t)grow * ASTR + kc * 2 + c * 16;
            char* la = (char*)As + (size_t)(wave * 128 + q * 64) * 16;
            llds16(ga, la);
            const char* gb = (const char*)Bw + (size_t)(colBase + r) * BSTR + k0 * 2 + c * 16;
            char* lb = (char*)Bs + (size_t)(wave * 128 + q * 64) * 16;
            llds16(gb, lb);
        }
        __syncthreads();
        short8 af[4], bf_[4];
#pragma unroll
        for (int i = 0; i < 4; ++i)
            af[i] = *(const short8*)&As[(wr + i * 16 + lm) * 32 + lq * 8];
#pragma unroll
        for (int j = 0; j < 4; ++j)
            bf_[j] = *(const short8*)&Bs[(wc + j * 16 + lm) * 32 + lq * 8];
#pragma unroll
        for (int i = 0; i < 4; ++i)
#pragma unroll
            for (int j = 0; j < 4; ++j)
                acc[i][j] = __builtin_amdgcn_mfma_f32_16x16x32_bf16(
                    af[i], bf_[j], acc[i][j], 0, 0, 0);
        __syncthreads();
    }

    // epilogue
#pragma unroll
    for (int i = 0; i < 4; ++i) {
#pragma unroll
        for (int r = 0; r < 4; ++r) {
            int row = rowBase + wr + i * 16 + lq * 4 + r;
            if (row >= NN) continue;
            size_t rb = (size_t)row * HID;
#pragma unroll
            for (int j = 0; j < 4; ++j) {
                int col = colBase + wc + j * 16 + lm;
                float v = acc[i][j][r] + bias[col];
                if (MODE == 0) {
                    Out[rb + col] = f2bf(fmaxf(v, 0.f));
                    Out[rb + col + 128] = 0;
                } else if (MODE == 1) {
                    float f = 1.f / (1.f + __expf(-v));
                    float hv = bf2f(Hh[rb + col]);
                    Ff[rb + col] = f2bf(f);
                    HF[rb + col] = f2bf(f * hv);
                } else {
                    float xc = fminf(fmaxf(v, -12.f), 12.f);
                    float e2 = __expf(2.f * xc);
                    float t = (e2 - 1.f) / (e2 + 1.f);
                    float f = bf2f(Ff[rb + col]);
                    float hv = bf2f(Hh[rb + col]);
                    Out[rb + col] = f2bf((1.f - f) * hv + f * t);
                }
            }
        }
    }
}

// ---------------------------------------------------------------------------
// Readout
// ---------------------------------------------------------------------------
__global__ __launch_bounds__(256)
void colmean(const unsigned short* __restrict__ h, float* __restrict__ gsum) {
    int j = threadIdx.x;
    long long n0 = (long long)blockIdx.x * 256;
    float acc = 0.0f;
    for (int n = 0; n < 256; ++n) {
        long long node = n0 + n;
        if (node < NN) acc += bf2f(h[node * HID + j]);
    }
    atomicAdd(&gsum[j], acc);
}

__global__ __launch_bounds__(256)
void final_pred(const float* __restrict__ gsum, const float* __restrict__ Wp,
                const float* __restrict__ bp, float* __restrict__ out) {
    __shared__ float s[256];
    int j = threadIdx.x;
    s[j] = gsum[j] * (1.0f / (float)NN) * Wp[j];
    __syncthreads();
    for (int ofs = 128; ofs > 0; ofs >>= 1) {
        if (j < ofs) s[j] += s[j + ofs];
        __syncthreads();
    }
    if (j == 0) out[0] = s[0] + bp[0];
}

// ---------------------------------------------------------------------------
extern "C" void kernel_launch(void* const* d_in, const int* in_sizes, int n_in,
                              void* d_out, int out_size, void* d_ws, size_t ws_size,
                              hipStream_t stream) {
    const float* x      = (const float*)d_in[0];
    const int*   ei     = (const int*)d_in[1];
    const float* W_in   = (const float*)d_in[2];
    const float* b_in   = (const float*)d_in[3];
    const float* W_f    = (const float*)d_in[4];
    const float* U_f    = (const float*)d_in[5];
    const float* b_f    = (const float*)d_in[6];
    const float* W_h    = (const float*)d_in[7];
    const float* U_h    = (const float*)d_in[8];
    const float* b_h    = (const float*)d_in[9];
    const float* W_pred = (const float*)d_in[10];
    const float* b_pred = (const float*)d_in[11];
    float* out = (float*)d_out;

    char* p = (char*)d_ws;
    auto alloc = [&](size_t bytes) {
        char* r = p;
        p += (bytes + 511) & ~(size_t)511;
        return r;
    };
    int*            cnt    = (int*)alloc((size_t)NN * 4);
    int*            cursor = (int*)alloc((size_t)NN * 4);
    int*            off    = (int*)alloc((size_t)(NN + 1) * 4);
    int*            flag   = (int*)alloc(4);
    float*          gsum   = (float*)alloc(HID * 4);
    int*            loc    = (int*)alloc((size_t)NN * 4);
    int*            bsum   = (int*)alloc((size_t)NBLK * 4);
    int*            bpre   = (int*)alloc((size_t)(NBLK + 1) * 4);
    unsigned short* wcf    = (unsigned short*)alloc((size_t)256 * 512 * 2);
    unsigned short* wch    = (unsigned short*)alloc((size_t)256 * 512 * 2);
    unsigned short* wib    = (unsigned short*)alloc((size_t)128 * 128 * 2);
    int*            csr    = (int*)alloc((size_t)NE * 4);
    unsigned short* hbuf   = (unsigned short*)alloc((size_t)NN * HID * 2);
    unsigned short* mbuf   = (unsigned short*)alloc((size_t)NN * HID * 2);
    unsigned short* fbuf   = (unsigned short*)alloc((size_t)NN * HID * 2);
    unsigned short* hf     = (unsigned short*)alloc((size_t)NN * HID * 2);
    unsigned short* xb     = hf;   // xb (25.6MB) used only before hf is live

    detect_i64<<<1, 64, 0, stream>>>(ei, flag);
    zero_setup<<<NBLK, 256, 0, stream>>>(cnt, cursor, gsum);
    conv_weights<<<512, 256, 0, stream>>>(W_f, U_f, W_h, U_h, W_in, wcf, wch, wib);
    conv_x<<<(NN * 128 / 4 + 255) / 256, 256, 0, stream>>>(x, xb);

    count_deg<<<(NE + 255) / 256, 256, 0, stream>>>(ei, flag, cnt);
    scan_k1<<<NBLK, 256, 0, stream>>>(cnt, loc, bsum);
    scan_k2<<<1, 512, 0, stream>>>(bsum, bpre);
    scan_k3<<<NBLK, 256, 0, stream>>>(loc, bpre, off);
    fill_csr<<<(NE + 255) / 256, 256, 0, stream>>>(ei, flag, off, cursor, csr);

    const int MBLK = (NN + 127) / 128;   // 782
    // input encode: h = relu(x @ W_in^T + b_in), zero-padded to 256
    gemm_mfma<0><<<dim3(MBLK, 1), 256, 0, stream>>>(
        xb, nullptr, wib, b_in, nullptr, nullptr, nullptr, hbuf);

    for (int step = 0; step < 4; ++step) {
        aggregate<<<NN / 4, 256, 0, stream>>>(hbuf, off, csr, mbuf);
        gemm_mfma<1><<<dim3(MBLK, 2), 256, 0, stream>>>(
            mbuf, hbuf, wcf, b_f, hbuf, fbuf, hf, nullptr);
        gemm_mfma<2><<<dim3(MBLK, 2), 256, 0, stream>>>(
            mbuf, hf, wch, b_h, hbuf, fbuf, nullptr, hbuf);
    }

    colmean<<<NBLK, 256, 0, stream>>>(hbuf, gsum);
    final_pred<<<1, 256, 0, stream>>>(gsum, W_pred, b_pred, out);
}